// Round 5
// baseline (1491.408 us; speedup 1.0000x reference)
//
#include <hip/hip_runtime.h>

// x:   (2,4,8,8,8,96,96) fp32   strides: b 18874368, ci 4718592, cd 589824, t 73728, d 9216, h 96, w 1
// W:   (9,4,4,3,3,3)     fp32
// b:   (9,4)             fp32
// out: (2,4,6,6,8,96,96) fp32
//
// Round-5: round-2 body (256,4) + weights BACK in LDS.
// Evidence trail:
//  - r3: x-prefetch neutral -> x-load latency already hidden by TLP.
//  - r4: (256,8) hurt; occupancy pinned ~40% regardless of resources.
//  - r1-r4 all read weights from global in the compute phase: 9 VMEM
//    float4 loads/iter with near-immediate use = ~450-900 cyc exposed
//    latency per ~1300 busy cyc == the observed ~34% VALU idle.
// Weights are wave-uniform -> LDS reads broadcast (conflict-free, imm
// offsets, no VMEM in compute). LDS 38.2KB -> 4 blocks/CU (residency is
// pinned there anyway).
// Kept from r2: stride-105 xs (read conflict-free), zero-once halos,
// precomputed staging descriptors, short-live-range staging (no spill).

#define BLOCK 256
#define XSTRIDE 105

__global__ void prep_kernel(const float* __restrict__ Wg,
                            const float* __restrict__ bg,
                            float* __restrict__ ws)
{
    int k = blockIdx.x * blockDim.x + threadIdx.x;
    if (k < 3888) {
        int o  = k & 3;  int r = k >> 2;
        int kw = r % 3;  r /= 3;
        int kh = r % 3;  r /= 3;
        int kd = r % 3;  r /= 3;
        int ij = r % 9;  int ci = r / 9;
        ws[k] = Wg[ij*432 + o*108 + ci*27 + kd*9 + kh*3 + kw];
    }
    if (k < 4) {
        float s = 0.f;
        #pragma unroll
        for (int ij = 0; ij < 9; ++ij) s += bg[ij*4 + k];
        ws[3888 + k] = s * (1.0f / 9.0f);
    }
}

__global__ __launch_bounds__(256, 4) void conv5d_kernel(
    const float* __restrict__ xg,
    const float* __restrict__ wsW,
    float* __restrict__ outg)
{
    __shared__ float4 wl4[973];          // weights [ci][ij][kd][kh][kw][o] + mb
    __shared__ float  xs[54 * XSTRIDE];  // 22680 B; total LDS 38.2 KB
    float* wl = (float*)wl4;

    // stage weights (linear float4 copy from repacked workspace)
    for (int k = threadIdx.x; k < 973; k += BLOCK)
        wl4[k] = ((const float4*)wsW)[k];
    // zero xs once: w-halo cols (idx 3/100) and invalid d/h rows never re-staged
    for (int k = threadIdx.x; k < 54 * XSTRIDE; k += BLOCK) xs[k] = 0.f;

    // XCD-aware block decode: 3456 blocks = 72 (b,c,t) slabs x 48 (d,ht).
    int bi   = blockIdx.x;
    int xcd  = bi & 7;
    int g    = bi >> 3;
    int slab = xcd*9 + g/48;
    int r2   = g % 48;
    int d    = r2 / 6;
    int ht   = r2 % 6;
    int b    = slab / 36;
    int ct   = slab % 36;
    int c    = ct / 6;
    int t    = ct % 6;
    int h0   = ht * 16;

    int wt     = threadIdx.x & 15;   // w0 = 6*wt
    int hr_out = threadIdx.x >> 4;   // 0..15

    // ---- loop-invariant staging descriptors ----
    int  goff[6];
    int  lw[6];
    bool pv[6];
    #pragma unroll
    for (int p = 0; p < 6; ++p) {
        int u   = threadIdx.x + p*BLOCK;   // valid < 1296
        int row = u / 24;
        int q   = u % 24;
        int pl  = row / 18;
        int hr  = row % 18;
        int dd  = d + pl - 1;
        int hh  = h0 + hr - 1;
        pv[p]   = (u < 1296) && ((unsigned)dd < 8u) && ((unsigned)hh < 96u);
        goff[p] = dd*9216 + hh*96 + q*4;
        lw[p]   = row*XSTRIDE + 4 + q*4;
    }

    float acc[4][6] = {};

    #pragma unroll 1
    for (int it = 0; it < 36; ++it) {
        int ci = it / 9;
        int ij = it % 9;
        int i  = ij / 3;
        int j  = ij % 3;
        const float* xp = xg + (size_t)b*18874368 + (size_t)ci*4718592
                             + (size_t)(c + i)*589824
                             + (size_t)(t + j)*73728;

        __syncthreads();   // prev iter's readers (and init fills) done

        // ---- stage: 6 global loads -> LDS (short live range, no spill) ----
        float4 v[6];
        #pragma unroll
        for (int p = 0; p < 6; ++p)
            if (pv[p]) v[p] = *(const float4*)(xp + goff[p]);
        #pragma unroll
        for (int p = 0; p < 6; ++p) {
            if (pv[p]) {
                xs[lw[p] + 0] = v[p].x;
                xs[lw[p] + 1] = v[p].y;
                xs[lw[p] + 2] = v[p].z;
                xs[lw[p] + 3] = v[p].w;
            }
        }
        __syncthreads();

        // ---- compute: 648 FMAs; weights via LDS broadcast (imm offsets) ----
        const float4* wq4 = (const float4*)(wl + (ci*9 + ij)*108);
        #pragma unroll
        for (int pl = 0; pl < 3; ++pl) {
            #pragma unroll
            for (int kh = 0; kh < 3; ++kh) {
                const float* xr = &xs[(pl*18 + hr_out + kh)*XSTRIDE + 3 + 6*wt];
                float x0 = xr[0], x1 = xr[1], x2 = xr[2], x3 = xr[3];
                float x4 = xr[4], x5 = xr[5], x6 = xr[6], x7 = xr[7];
                float xv[8] = {x0, x1, x2, x3, x4, x5, x6, x7};
                const float4* wr = wq4 + (pl*3 + kh)*3;
                float4 wk0 = wr[0];
                float4 wk1 = wr[1];
                float4 wk2 = wr[2];
                #pragma unroll
                for (int vv = 0; vv < 6; ++vv) {
                    float a = xv[vv], bb = xv[vv+1], cc = xv[vv+2];
                    acc[0][vv] = fmaf(a,  wk0.x, acc[0][vv]);
                    acc[1][vv] = fmaf(a,  wk0.y, acc[1][vv]);
                    acc[2][vv] = fmaf(a,  wk0.z, acc[2][vv]);
                    acc[3][vv] = fmaf(a,  wk0.w, acc[3][vv]);
                    acc[0][vv] = fmaf(bb, wk1.x, acc[0][vv]);
                    acc[1][vv] = fmaf(bb, wk1.y, acc[1][vv]);
                    acc[2][vv] = fmaf(bb, wk1.z, acc[2][vv]);
                    acc[3][vv] = fmaf(bb, wk1.w, acc[3][vv]);
                    acc[0][vv] = fmaf(cc, wk2.x, acc[0][vv]);
                    acc[1][vv] = fmaf(cc, wk2.y, acc[1][vv]);
                    acc[2][vv] = fmaf(cc, wk2.z, acc[2][vv]);
                    acc[3][vv] = fmaf(cc, wk2.w, acc[3][vv]);
                }
            }
        }
    }

    float mb[4] = {wl[3888], wl[3889], wl[3890], wl[3891]};

    const float inv9 = 1.0f / 9.0f;
    size_t obase = (size_t)b*10616832 + (size_t)c*442368 + (size_t)t*73728
                 + (size_t)d*9216 + (size_t)(h0 + hr_out)*96 + 6*wt;
    #pragma unroll
    for (int o = 0; o < 4; ++o) {
        float* op = outg + obase + (size_t)o*2654208;
        #pragma unroll
        for (int vv = 0; vv < 3; ++vv) {
            float2 st;
            st.x = acc[o][2*vv]   * inv9 + mb[o];
            st.y = acc[o][2*vv+1] * inv9 + mb[o];
            *(float2*)(op + 2*vv) = st;
        }
    }
}

extern "C" void kernel_launch(void* const* d_in, const int* in_sizes, int n_in,
                              void* d_out, int out_size, void* d_ws, size_t ws_size,
                              hipStream_t stream) {
    const float* x = (const float*)d_in[0];
    const float* W = (const float*)d_in[1];
    const float* b = (const float*)d_in[2];
    float* out = (float*)d_out;
    float* ws  = (float*)d_ws;

    prep_kernel<<<16, BLOCK, 0, stream>>>(W, b, ws);
    conv5d_kernel<<<3456, BLOCK, 0, stream>>>(x, ws, out);
}

// Round 6
// 685.005 us; speedup vs baseline: 2.1772x; 2.1772x over previous
//
#include <hip/hip_runtime.h>

// x:   (2,4,8,8,8,96,96) fp32   strides: b 18874368, ci 4718592, cd 589824, t 73728, d 9216, h 96, w 1
// W:   (9,4,4,3,3,3)     fp32
// b:   (9,4)             fp32
// out: (2,4,6,6,8,96,96) fp32
//
// Round-6: r2 body (proven clean: 586us, no spill) with ONE change:
// LDS reads vectorized to ds_read_b64.
// Evidence: r2's LDS-unit demand = 72 b32 reads + 24 b32 writes per
// thread-iter = ~494us of the 586us total -> LDS-throughput-bound.
// (r3: x-prefetch neutral; r4: more waves hurt; r5: weights-in-LDS spilled
// — all consistent with LDS pipe, not VMEM/VALU, being the limiter.)
// Change: XSTRIDE 105 -> 106 (424B rows, 8B-aligned) with w=0 at idx 5,
// so compute reads start at even idx 4+6*wt -> float2/ds_read_b64 (36
// instead of 72 read instrs). Bank math: hr-groups at row offsets
// {0,10,20,30} mod 32, each covering all 32 banks once -> 4 accesses/bank
// per b64 = the 512B minimum = conflict-free. Staging writes stay 4x b32
// (odd base); weights stay in global (r5's LDS move spilled).

#define BLOCK 256
#define XSTRIDE 106

__global__ void prep_kernel(const float* __restrict__ Wg,
                            const float* __restrict__ bg,
                            float* __restrict__ ws)
{
    int k = blockIdx.x * blockDim.x + threadIdx.x;
    if (k < 3888) {
        int o  = k & 3;  int r = k >> 2;
        int kw = r % 3;  r /= 3;
        int kh = r % 3;  r /= 3;
        int kd = r % 3;  r /= 3;
        int ij = r % 9;  int ci = r / 9;
        ws[k] = Wg[ij*432 + o*108 + ci*27 + kd*9 + kh*3 + kw];
    }
    if (k < 4) {
        float s = 0.f;
        #pragma unroll
        for (int ij = 0; ij < 9; ++ij) s += bg[ij*4 + k];
        ws[3888 + k] = s * (1.0f / 9.0f);
    }
}

__global__ __launch_bounds__(256, 4) void conv5d_kernel(
    const float* __restrict__ xg,
    const float* __restrict__ wsW,
    float* __restrict__ outg)
{
    __shared__ float xs[54 * XSTRIDE];   // 22896 B

    // zero once: w-halo cols (idx 4 / 101) and out-of-range d/h rows are
    // never re-staged afterwards.
    for (int k = threadIdx.x; k < 54 * XSTRIDE; k += BLOCK) xs[k] = 0.f;

    // XCD-aware block decode: 3456 blocks = 72 (b,c,t) slabs x 48 (d,ht).
    int bi   = blockIdx.x;
    int xcd  = bi & 7;
    int g    = bi >> 3;
    int slab = xcd*9 + g/48;
    int r2   = g % 48;
    int d    = r2 / 6;
    int ht   = r2 % 6;
    int b    = slab / 36;
    int ct   = slab % 36;
    int c    = ct / 6;
    int t    = ct % 6;
    int h0   = ht * 16;

    int wt     = threadIdx.x & 15;   // w0 = 6*wt
    int hr_out = threadIdx.x >> 4;   // 0..15

    // ---- loop-invariant staging descriptors ----
    int  goff[6];
    int  lw[6];
    bool pv[6];
    #pragma unroll
    for (int p = 0; p < 6; ++p) {
        int u   = threadIdx.x + p*BLOCK;   // valid < 1296
        int row = u / 24;
        int q   = u % 24;
        int pl  = row / 18;
        int hr  = row % 18;
        int dd  = d + pl - 1;
        int hh  = h0 + hr - 1;
        pv[p]   = (u < 1296) && ((unsigned)dd < 8u) && ((unsigned)hh < 96u);
        goff[p] = dd*9216 + hh*96 + q*4;
        lw[p]   = row*XSTRIDE + 5 + q*4;   // w=0 at idx 5
    }

    float acc[4][6] = {};

    #pragma unroll 1
    for (int it = 0; it < 36; ++it) {
        int ci = it / 9;
        int ij = it % 9;
        int i  = ij / 3;
        int j  = ij % 3;
        const float* xp = xg + (size_t)b*18874368 + (size_t)ci*4718592
                             + (size_t)(c + i)*589824
                             + (size_t)(t + j)*73728;

        __syncthreads();   // previous iter's readers done before overwrite

        // ---- stage: 6 global loads -> LDS (short live range, no spill) ----
        float4 v[6];
        #pragma unroll
        for (int p = 0; p < 6; ++p)
            if (pv[p]) v[p] = *(const float4*)(xp + goff[p]);
        #pragma unroll
        for (int p = 0; p < 6; ++p) {
            if (pv[p]) {
                xs[lw[p] + 0] = v[p].x;
                xs[lw[p] + 1] = v[p].y;
                xs[lw[p] + 2] = v[p].z;
                xs[lw[p] + 3] = v[p].w;
            }
        }
        __syncthreads();

        // ---- compute: 9 rows x (3 kw x 6 w x 4 o) = 648 FMAs ----
        const float4* wq4 = (const float4*)(wsW + (ci*9 + ij)*108);
        #pragma unroll
        for (int pl = 0; pl < 3; ++pl) {
            #pragma unroll
            for (int kh = 0; kh < 3; ++kh) {
                // taps w0-1..w0+6 at idx (4+6wt)..(11+6wt): even base,
                // 8B-aligned rows -> 4x ds_read_b64, conflict-free
                const float2* xr2 = (const float2*)
                    &xs[(pl*18 + hr_out + kh)*XSTRIDE + 4 + 6*wt];
                float2 p0 = xr2[0], p1 = xr2[1], p2 = xr2[2], p3 = xr2[3];
                float xv[8] = {p0.x, p0.y, p1.x, p1.y, p2.x, p2.y, p3.x, p3.y};
                const float4* wr = wq4 + (pl*3 + kh)*3;
                float4 wk0 = wr[0];
                float4 wk1 = wr[1];
                float4 wk2 = wr[2];
                #pragma unroll
                for (int vv = 0; vv < 6; ++vv) {
                    float a = xv[vv], bb = xv[vv+1], cc = xv[vv+2];
                    acc[0][vv] = fmaf(a,  wk0.x, acc[0][vv]);
                    acc[1][vv] = fmaf(a,  wk0.y, acc[1][vv]);
                    acc[2][vv] = fmaf(a,  wk0.z, acc[2][vv]);
                    acc[3][vv] = fmaf(a,  wk0.w, acc[3][vv]);
                    acc[0][vv] = fmaf(bb, wk1.x, acc[0][vv]);
                    acc[1][vv] = fmaf(bb, wk1.y, acc[1][vv]);
                    acc[2][vv] = fmaf(bb, wk1.z, acc[2][vv]);
                    acc[3][vv] = fmaf(bb, wk1.w, acc[3][vv]);
                    acc[0][vv] = fmaf(cc, wk2.x, acc[0][vv]);
                    acc[1][vv] = fmaf(cc, wk2.y, acc[1][vv]);
                    acc[2][vv] = fmaf(cc, wk2.z, acc[2][vv]);
                    acc[3][vv] = fmaf(cc, wk2.w, acc[3][vv]);
                }
            }
        }
    }

    float4 mb4 = *(const float4*)(wsW + 3888);
    float mb[4] = {mb4.x, mb4.y, mb4.z, mb4.w};

    const float inv9 = 1.0f / 9.0f;
    size_t obase = (size_t)b*10616832 + (size_t)c*442368 + (size_t)t*73728
                 + (size_t)d*9216 + (size_t)(h0 + hr_out)*96 + 6*wt;
    #pragma unroll
    for (int o = 0; o < 4; ++o) {
        float* op = outg + obase + (size_t)o*2654208;
        #pragma unroll
        for (int vv = 0; vv < 3; ++vv) {
            float2 st;
            st.x = acc[o][2*vv]   * inv9 + mb[o];
            st.y = acc[o][2*vv+1] * inv9 + mb[o];
            *(float2*)(op + 2*vv) = st;
        }
    }
}

extern "C" void kernel_launch(void* const* d_in, const int* in_sizes, int n_in,
                              void* d_out, int out_size, void* d_ws, size_t ws_size,
                              hipStream_t stream) {
    const float* x = (const float*)d_in[0];
    const float* W = (const float*)d_in[1];
    const float* b = (const float*)d_in[2];
    float* out = (float*)d_out;
    float* ws  = (float*)d_ws;

    prep_kernel<<<16, BLOCK, 0, stream>>>(W, b, ws);
    conv5d_kernel<<<3456, BLOCK, 0, stream>>>(x, ws, out);
}